// Round 5
// baseline (244.372 us; speedup 1.0000x reference)
//
#include <hip/hip_runtime.h>
#include <hip/hip_bf16.h>

#define BATCH 1024
#define SEQ 256
#define HIDDEN 128
#define VOCAB 60
#define ROWS 4             // batch rows per PROBLEM (MFMA n-dim aliased 4x)
#define NPROB 2            // independent recurrences interleaved per block
#define BROWS (ROWS*NPROB) // 8 batch rows per block
#define CHUNK 16           // ring-buffer depth in time steps
#define ASTRIDE 144        // f16 per h row: 72 dw == 8 mod 32 -> max 2-way (free)
#define RSTR 136           // f32 per ring row: 136 == 8 mod 32 -> conflict-free b128
#define XSTR 260           // ints per xs row (alignment pad)

typedef _Float16 f16x8 __attribute__((ext_vector_type(8)));
typedef float f32x4 __attribute__((ext_vector_type(4)));

__device__ __forceinline__ float fast_tanh(float x) {
    // tanh(x) = 1 - 2/(exp(2x)+1); exp(2x)=exp2(x*2*log2e). Branch-free, exact +-1 tails.
    float e = __builtin_amdgcn_exp2f(x * 2.8853900817779268f);
    return __builtin_fmaf(-2.0f, __builtin_amdgcn_rcpf(e + 1.0f), 1.0f);
}

__device__ __forceinline__ f32x4 MF(f16x8 a, f16x8 b, f32x4 c) {
    return __builtin_amdgcn_mfma_f32_16x16x32_f16(a, b, c, 0, 0, 0);
}

// lgkm-only step barrier (R19-verified): in-loop cross-wave traffic is LDS
// only, so no vmcnt drain; prefetched chunk loads coast until their ds_write
// 16 steps later.
#define STEP_BARRIER() asm volatile("s_waitcnt lgkmcnt(0)\n\ts_barrier" ::: "memory")

// embW[v][i] = sum_j emb[v][j] * W_ih[i][j]  (fp32-exact input-projection table)
__global__ void rnn_prep_embw(const float* __restrict__ emb,
                              const float* __restrict__ W_ih,
                              float* __restrict__ embW) {
    const int v = blockIdx.x;
    const int i = threadIdx.x;
    __shared__ __align__(16) float e[HIDDEN];
    e[i] = emb[v * HIDDEN + i];
    __syncthreads();
    const float4* wrow = (const float4*)(W_ih + i * HIDDEN);
    const float4* e4 = (const float4*)e;
    float a0 = 0.f, a1 = 0.f, a2 = 0.f, a3 = 0.f;
#pragma unroll
    for (int j = 0; j < HIDDEN / 4; ++j) {
        float4 w = wrow[j];
        float4 h = e4[j];
        a0 += w.x * h.x; a1 += w.y * h.y; a2 += w.z * h.z; a3 += w.w * h.w;
    }
    embW[v * HIDDEN + i] = (a0 + a1) + (a2 + a3);
}

// R20: champion structure (8 waves, 2/SIMD, dedup'd ring staging) but each
// block runs TWO independent 4-row recurrences (T15 cross-problem ILP).
// Per superstep: step t of problem A and B between ONE lgkm-only barrier.
// B's DS reads/MFMAs/tanh fill A's exposed serial-chain latency (~450 cyc
// of the champion's 950 cyc step) and barrier count halves. W_hh frags are
// shared; ring/Ah/xs duplicate (LDS 87 KB, 1 block/CU). Grid 128 blocks --
// wall time depends only on per-block step time.
__global__ void __launch_bounds__(512)
rnn_mfma(const int* __restrict__ x, const int* __restrict__ lengths,
         const float* __restrict__ embW, const float* __restrict__ W_hh,
         const float* __restrict__ W_fc, const float* __restrict__ b_fc,
         float* __restrict__ out) {
    const int tid = threadIdx.x;
    const int wave = tid >> 6;   // 0..7
    const int lane = tid & 63;
    const int q = lane >> 4;     // 0..3
    const int r16 = lane & 15;   // MFMA n index
    const int r4 = r16 & 3;      // real batch row within problem (aliased 4x)
    const int c0 = wave * 16;    // wave's 16 z-cols
    const int b0 = blockIdx.x * BROWS;

    __shared__ __align__(16) float ring[NPROB][CHUNK][ROWS][RSTR];   // 69632 B
    __shared__ __align__(16) _Float16 Ah[NPROB][2][ROWS][ASTRIDE];   // 4608 B
    __shared__ __align__(16) int xs[BROWS][XSTR];                    // 8320 B
    __shared__ __align__(16) float hfin[BROWS][HIDDEN];              // 4096 B
    __shared__ int lenbuf[BROWS];

    // Stage tokens + lengths; zero both problems' h buffers.
    for (int idx = tid; idx < BROWS * SEQ; idx += 512) {
        int r = idx >> 8, t = idx & (SEQ - 1);
        xs[r][t] = x[(b0 + r) * SEQ + t];
    }
    if (tid < BROWS) lenbuf[tid] = lengths[b0 + tid];
    for (int idx = tid; idx < (int)(sizeof(Ah) / 4); idx += 512)
        ((int*)Ah)[idx] = 0;

    // Static A-frags of W_hh for this wave's 16-col slice (SHARED by A/B):
    // A[m=r16][k=kc*32+q*8+j] = W_hh[c0 + r16][kc*32 + q*8 + j]. 16 VGPRs.
    f16x8 Wf[4];
    {
        const float* wrow = W_hh + (c0 + r16) * HIDDEN + q * 8;
#pragma unroll
        for (int kc = 0; kc < 4; ++kc) {
            const float* p = wrow + kc * 32;
#pragma unroll
            for (int j = 0; j < 8; ++j) Wf[kc][j] = (_Float16)p[j];
        }
    }

    __syncthreads();  // xs / lenbuf / Ah visible

    const int mylen0 = lenbuf[r4];
    const int mylen1 = lenbuf[ROWS + r4];
    int lenmax = 0;
#pragma unroll
    for (int r = 0; r < BROWS; ++r) lenmax = max(lenmax, lenbuf[r]);

    // Staging-thread mapping (per problem, champion's dedup'd map):
    // thread -> (tp, r, c4); each of 512 threads loads 4 DISTINCT f32x4 per
    // problem per chunk (exactly covers 16 steps x 4 rows x 128 floats).
    const int s_c4 = tid & 31;
    const int s_r = (tid >> 5) & 3;
    const int s_tp = tid >> 7;   // 0..3, +4 per k

    // Prefetch chunk 0 seeds into registers (both problems).
    f32x4 rg0[4], rg1[4];
#pragma unroll
    for (int k = 0; k < 4; ++k) {
        int tp = s_tp + 4 * k;
        rg0[k] = *(const f32x4*)(embW + xs[s_r][tp] * HIDDEN + s_c4 * 4);
        rg1[k] = *(const f32x4*)(embW + xs[ROWS + s_r][tp] * HIDDEN + s_c4 * 4);
    }

    int cur = 0;
    f32x4 cap0 = {0.f, 0.f, 0.f, 0.f}, cap1 = {0.f, 0.f, 0.f, 0.f};

    for (int t0 = 0; t0 < lenmax; t0 += CHUNK) {
        // Boundary: staged regs -> rings (LDS only), then full barrier.
#pragma unroll
        for (int k = 0; k < 4; ++k) {
            *(f32x4*)&ring[0][s_tp + 4 * k][s_r][s_c4 * 4] = rg0[k];
            *(f32x4*)&ring[1][s_tp + 4 * k][s_r][s_c4 * 4] = rg1[k];
        }
        __syncthreads();

        // Issue next chunk's global loads now; consumed by ds_writes at the
        // NEXT boundary (16 supersteps away) -- never drained at a step
        // barrier (lgkm-only).
        if (t0 + CHUNK < lenmax) {
            const int t0n = t0 + CHUNK;
#pragma unroll
            for (int k = 0; k < 4; ++k) {
                int tp = t0n + s_tp + 4 * k;
                rg0[k] = *(const f32x4*)(embW + xs[s_r][tp] * HIDDEN + s_c4 * 4);
                rg1[k] = *(const f32x4*)(embW + xs[ROWS + s_r][tp] * HIDDEN + s_c4 * 4);
            }
        }

        const int tend = (lenmax - t0 < CHUNK) ? lenmax - t0 : CHUNK;
        for (int tt = 0; tt < tend; ++tt) {
            // --- combined superstep: problem A and B, one barrier ---
            const _Float16* hbA = &Ah[0][cur][r4][q * 8];
            const _Float16* hbB = &Ah[1][cur][r4][q * 8];
            f16x8 A0 = *(const f16x8*)(hbA + 0);
            f16x8 A1 = *(const f16x8*)(hbA + 32);
            f16x8 A2 = *(const f16x8*)(hbA + 64);
            f16x8 A3 = *(const f16x8*)(hbA + 96);
            f16x8 B0 = *(const f16x8*)(hbB + 0);
            f16x8 B1 = *(const f16x8*)(hbB + 32);
            f16x8 B2 = *(const f16x8*)(hbB + 64);
            f16x8 B3 = *(const f16x8*)(hbB + 96);

            f32x4 aA = *(const f32x4*)&ring[0][tt][r4][c0 + 4 * q];
            f32x4 aB = *(const f32x4*)&ring[1][tt][r4][c0 + 4 * q];
            f32x4 dA = {0.f, 0.f, 0.f, 0.f};
            f32x4 dB = {0.f, 0.f, 0.f, 0.f};

            // Interleave the two problems' chains: 4 independent MFMA deps.
            aA = MF(Wf[0], A0, aA);  aB = MF(Wf[0], B0, aB);
            dA = MF(Wf[2], A2, dA);  dB = MF(Wf[2], B2, dB);
            aA = MF(Wf[1], A1, aA);  aB = MF(Wf[1], B1, aB);
            dA = MF(Wf[3], A3, dA);  dB = MF(Wf[3], B3, dB);

            f32x4 zA = aA + dA, zB = aB + dB;
            f32x4 thA, thB;
            thA[0] = fast_tanh(zA[0]); thB[0] = fast_tanh(zB[0]);
            thA[1] = fast_tanh(zA[1]); thB[1] = fast_tanh(zB[1]);
            thA[2] = fast_tanh(zA[2]); thB[2] = fast_tanh(zB[2]);
            thA[3] = fast_tanh(zA[3]); thB[3] = fast_tanh(zB[3]);

            uint2 pA, pB;
            pA.x = __builtin_bit_cast(unsigned int, __builtin_amdgcn_cvt_pkrtz(thA[0], thA[1]));
            pA.y = __builtin_bit_cast(unsigned int, __builtin_amdgcn_cvt_pkrtz(thA[2], thA[3]));
            pB.x = __builtin_bit_cast(unsigned int, __builtin_amdgcn_cvt_pkrtz(thB[0], thB[1]));
            pB.y = __builtin_bit_cast(unsigned int, __builtin_amdgcn_cvt_pkrtz(thB[2], thB[3]));

            const int nxt = cur ^ 1;
            if (r16 < ROWS) {  // one writer per (problem, row, col-quad)
                *(uint2*)&Ah[0][nxt][r16][c0 + 4 * q] = pA;
                *(uint2*)&Ah[1][nxt][r16][c0 + 4 * q] = pB;
            }
            if (t0 + tt + 1 == mylen0) cap0 = thA;
            if (t0 + tt + 1 == mylen1) cap1 = thB;
            STEP_BARRIER();
            cur = nxt;
        }
    }

    // Final h (fp32 captures) -> hfin, then FC epilogue.
    if (r16 < ROWS) {
        *(f32x4*)&hfin[r16][c0 + 4 * q] = cap0;
        *(f32x4*)&hfin[ROWS + r16][c0 + 4 * q] = cap1;
    }
    __syncthreads();

    // FC: thread (r, c) computes out[b0+r][c].  512 = 8 rows x 64 slots.
    const int r = tid >> 6;      // 0..7
    const int c = tid & 63;      // 0..63
    if (c < VOCAB) {
        const float4* hv = (const float4*)hfin[r];
        const float4* wf = (const float4*)(W_fc + c * HIDDEN);
        float a0 = 0.f, a1 = 0.f, a2 = 0.f, a3 = 0.f;
#pragma unroll
        for (int j = 0; j < HIDDEN / 4; ++j) {
            float4 h = hv[j];
            float4 w = wf[j];
            a0 += h.x * w.x; a1 += h.y * w.y; a2 += h.z * w.z; a3 += h.w * w.w;
        }
        out[(b0 + r) * VOCAB + c] = (a0 + a1) + (a2 + a3) + b_fc[c];
    }
}

extern "C" void kernel_launch(void* const* d_in, const int* in_sizes, int n_in,
                              void* d_out, int out_size, void* d_ws, size_t ws_size,
                              hipStream_t stream) {
    const int* x = (const int*)d_in[0];          // [B, T] int32
    const int* lengths = (const int*)d_in[1];    // [B] int32
    const float* emb = (const float*)d_in[2];    // [V, H]
    const float* W_ih = (const float*)d_in[3];   // [H, H]
    const float* W_hh = (const float*)d_in[4];   // [H, H]
    const float* W_fc = (const float*)d_in[5];   // [V, H]
    const float* b_fc = (const float*)d_in[6];   // [V]
    float* out = (float*)d_out;                  // [B, V]

    float* embW = (float*)d_ws;                  // VOCAB*HIDDEN floats (30 KB)

    rnn_prep_embw<<<VOCAB, HIDDEN, 0, stream>>>(emb, W_ih, embW);
    rnn_mfma<<<BATCH / BROWS, 512, 0, stream>>>(x, lengths, embW, W_hh, W_fc, b_fc, out);
}

// Round 6
// 183.533 us; speedup vs baseline: 1.3315x; 1.3315x over previous
//
#include <hip/hip_runtime.h>
#include <hip/hip_bf16.h>

#define BATCH 1024
#define SEQ 256
#define HIDDEN 128
#define VOCAB 60
#define ROWS 4             // real batch rows per block (MFMA n-dim aliased 4x)
#define CHUNK 16           // seeds held in registers per chunk (16 x f32x4)
#define ASTRIDE 144        // f16 per h row: 72 dw == 8 mod 32 -> max 2-way (free)
#define XSTR 260           // ints per xs row: 1040 B, 16B-aligned rows

typedef _Float16 f16x8 __attribute__((ext_vector_type(8)));
typedef float f32x4 __attribute__((ext_vector_type(4)));

__device__ __forceinline__ float fast_tanh(float x) {
    // tanh(x) = 1 - 2/(exp(2x)+1); exp(2x)=exp2(x*2*log2e). Branch-free, exact +-1 tails.
    float e = __builtin_amdgcn_exp2f(x * 2.8853900817779268f);
    return __builtin_fmaf(-2.0f, __builtin_amdgcn_rcpf(e + 1.0f), 1.0f);
}

__device__ __forceinline__ f32x4 MF(f16x8 a, f16x8 b, f32x4 c) {
    return __builtin_amdgcn_mfma_f32_16x16x32_f16(a, b, c, 0, 0, 0);
}

// lgkm-only step barrier (R19-verified: recovered 5.5us vs __syncthreads):
// in-loop cross-wave traffic is LDS-only, so no vmcnt drain -- the chunk's
// seed-load burst stays in flight across step barriers.
#define STEP_BARRIER() asm volatile("s_waitcnt lgkmcnt(0)\n\ts_barrier" ::: "memory")

// embW[v][i] = sum_j emb[v][j] * W_ih[i][j]  (fp32-exact input-projection table)
__global__ void rnn_prep_embw(const float* __restrict__ emb,
                              const float* __restrict__ W_ih,
                              float* __restrict__ embW) {
    const int v = blockIdx.x;
    const int i = threadIdx.x;
    __shared__ __align__(16) float e[HIDDEN];
    e[i] = emb[v * HIDDEN + i];
    __syncthreads();
    const float4* wrow = (const float4*)(W_ih + i * HIDDEN);
    const float4* e4 = (const float4*)e;
    float a0 = 0.f, a1 = 0.f, a2 = 0.f, a3 = 0.f;
#pragma unroll
    for (int j = 0; j < HIDDEN / 4; ++j) {
        float4 w = wrow[j];
        float4 h = e4[j];
        a0 += w.x * h.x; a1 += w.y * h.y; a2 += w.z * h.z; a3 += w.w * h.w;
    }
    embW[v * HIDDEN + i] = (a0 + a1) + (a2 + a3);
}

// R21: champion 8-wave structure (2 waves/SIMD) with the ring deleted and
// chunk seeds held IN REGISTERS. Step model (fits all 5 prior measurements):
// step = DS-burst (N_DS x ~10cyc) + tail chain (~470cyc). Champion N_DS=48
// (32 H-reads + 8 writes + 8 ring-reads). Here the 8 ring-reads are gone:
// each lane loads its own 16 chunk seeds (embW[tok][c0+4q..+4), 4x lane-
// aliased) as a 16-instr VMEM burst at the chunk boundary -- 128 VMEM/CU
// amortized over 16 steps, off the DS pipe and off the critical path (lgkm-
// only barriers never drain vmcnt; first loads return ~300cyc < first H-read
// service ~400cyc). N_DS=40 -> predicted step ~870cyc. LDS drops to 8.7KB;
// +64 seed VGPRs (fine at 2 waves/SIMD).
__global__ void __launch_bounds__(512)
rnn_mfma(const int* __restrict__ x, const int* __restrict__ lengths,
         const float* __restrict__ embW, const float* __restrict__ W_hh,
         const float* __restrict__ W_fc, const float* __restrict__ b_fc,
         float* __restrict__ out) {
    const int tid = threadIdx.x;
    const int wave = tid >> 6;   // 0..7
    const int lane = tid & 63;
    const int q = lane >> 4;     // 0..3
    const int r16 = lane & 15;   // MFMA n index
    const int r4 = r16 & 3;      // real batch row (aliased 4x)
    const int c0 = wave * 16;    // wave's 16 z-cols
    const int b0 = blockIdx.x * ROWS;

    __shared__ __align__(16) _Float16 Ah[2][ROWS][ASTRIDE];   // 2304 B
    __shared__ __align__(16) int xs[ROWS][XSTR];              // 4160 B
    __shared__ __align__(16) float hfin[ROWS][HIDDEN];        // 2048 B
    __shared__ int lenbuf[ROWS];

    // Stage tokens + lengths; zero both h buffers.
    for (int idx = tid; idx < ROWS * SEQ; idx += 512) {
        int r = idx >> 8, t = idx & (SEQ - 1);
        xs[r][t] = x[(b0 + r) * SEQ + t];
    }
    if (tid < ROWS) lenbuf[tid] = lengths[b0 + tid];
    for (int idx = tid; idx < (int)(sizeof(Ah) / 4); idx += 512)
        ((int*)Ah)[idx] = 0;

    // Static A-frags of W_hh for this wave's 16-col slice:
    // A[m=r16][k=kc*32+q*8+j] = W_hh[c0 + r16][kc*32 + q*8 + j]. 16 VGPRs.
    f16x8 Wf[4];
    {
        const float* wrow = W_hh + (c0 + r16) * HIDDEN + q * 8;
#pragma unroll
        for (int kc = 0; kc < 4; ++kc) {
            const float* p = wrow + kc * 32;
#pragma unroll
            for (int j = 0; j < 8; ++j) Wf[kc][j] = (_Float16)p[j];
        }
    }

    __syncthreads();  // xs / lenbuf / Ah visible

    const int mylen = lenbuf[r4];
    int lenmax = 0;
#pragma unroll
    for (int r = 0; r < ROWS; ++r) lenmax = max(lenmax, lenbuf[r]);
    const int lenpad = (lenmax + CHUNK - 1) & ~(CHUNK - 1);  // pad to x16;
    // extra steps compute garbage h from valid-but-unused seeds, never
    // captured (mylen <= lenmax).

    // Per-lane seed base: embW[tok][c0 + 4q .. +3].
    const float* eb0 = embW + c0 + 4 * q;

    int cur = 0;
    f32x4 cap = {0.f, 0.f, 0.f, 0.f};

// One recurrence step: 4 broadcast H-reads feed 4 MFMAs (2 chains), tanh x4,
// pack, 1 b64 write (r16<4 lanes), capture, lgkm-only barrier.
#define STEP(TT, SA) do {                                                  \
    const _Float16* hb = &Ah[cur][r4][q * 8];                              \
    f16x8 H0 = *(const f16x8*)(hb + 0);                                    \
    f16x8 H1 = *(const f16x8*)(hb + 32);                                   \
    f16x8 H2 = *(const f16x8*)(hb + 64);                                   \
    f16x8 H3 = *(const f16x8*)(hb + 96);                                   \
    f32x4 a = (SA);                                                        \
    f32x4 d = {0.f, 0.f, 0.f, 0.f};                                        \
    a = MF(Wf[0], H0, a);                                                  \
    d = MF(Wf[2], H2, d);                                                  \
    a = MF(Wf[1], H1, a);                                                  \
    d = MF(Wf[3], H3, d);                                                  \
    f32x4 z = a + d;                                                       \
    f32x4 th;                                                              \
    th[0] = fast_tanh(z[0]); th[1] = fast_tanh(z[1]);                      \
    th[2] = fast_tanh(z[2]); th[3] = fast_tanh(z[3]);                      \
    uint2 pk;                                                              \
    pk.x = __builtin_bit_cast(unsigned int, __builtin_amdgcn_cvt_pkrtz(th[0], th[1])); \
    pk.y = __builtin_bit_cast(unsigned int, __builtin_amdgcn_cvt_pkrtz(th[2], th[3])); \
    const int nxt = cur ^ 1;                                               \
    if (r16 < ROWS)  /* one writer per (row, col-quad) */                  \
        *(uint2*)&Ah[nxt][r16][c0 + 4 * q] = pk;                           \
    if ((TT) + 1 == mylen) cap = th;                                       \
    STEP_BARRIER();                                                        \
    cur = nxt;                                                             \
} while (0)

    for (int t0 = 0; t0 < lenpad; t0 += CHUNK) {
        // Chunk boundary: read 16 tokens (4 int4 LDS reads, 16B-aligned:
        // row base 1040B, t0 multiple of 16) and issue the 16-seed VMEM
        // burst. Service (~128 instrs/CU x ~16cyc) amortizes over 16 steps.
        int4 ta = *(const int4*)&xs[r4][t0 + 0];
        int4 tb = *(const int4*)&xs[r4][t0 + 4];
        int4 tc = *(const int4*)&xs[r4][t0 + 8];
        int4 td = *(const int4*)&xs[r4][t0 + 12];
        f32x4 sd0  = *(const f32x4*)(eb0 + ta.x * HIDDEN);
        f32x4 sd1  = *(const f32x4*)(eb0 + ta.y * HIDDEN);
        f32x4 sd2  = *(const f32x4*)(eb0 + ta.z * HIDDEN);
        f32x4 sd3  = *(const f32x4*)(eb0 + ta.w * HIDDEN);
        f32x4 sd4  = *(const f32x4*)(eb0 + tb.x * HIDDEN);
        f32x4 sd5  = *(const f32x4*)(eb0 + tb.y * HIDDEN);
        f32x4 sd6  = *(const f32x4*)(eb0 + tb.z * HIDDEN);
        f32x4 sd7  = *(const f32x4*)(eb0 + tb.w * HIDDEN);
        f32x4 sd8  = *(const f32x4*)(eb0 + tc.x * HIDDEN);
        f32x4 sd9  = *(const f32x4*)(eb0 + tc.y * HIDDEN);
        f32x4 sd10 = *(const f32x4*)(eb0 + tc.z * HIDDEN);
        f32x4 sd11 = *(const f32x4*)(eb0 + tc.w * HIDDEN);
        f32x4 sd12 = *(const f32x4*)(eb0 + td.x * HIDDEN);
        f32x4 sd13 = *(const f32x4*)(eb0 + td.y * HIDDEN);
        f32x4 sd14 = *(const f32x4*)(eb0 + td.z * HIDDEN);
        f32x4 sd15 = *(const f32x4*)(eb0 + td.w * HIDDEN);

        STEP(t0 + 0,  sd0);
        STEP(t0 + 1,  sd1);
        STEP(t0 + 2,  sd2);
        STEP(t0 + 3,  sd3);
        STEP(t0 + 4,  sd4);
        STEP(t0 + 5,  sd5);
        STEP(t0 + 6,  sd6);
        STEP(t0 + 7,  sd7);
        STEP(t0 + 8,  sd8);
        STEP(t0 + 9,  sd9);
        STEP(t0 + 10, sd10);
        STEP(t0 + 11, sd11);
        STEP(t0 + 12, sd12);
        STEP(t0 + 13, sd13);
        STEP(t0 + 14, sd14);
        STEP(t0 + 15, sd15);
    }
#undef STEP

    // Final h (fp32 captures) -> hfin, then FC epilogue.
    if (r16 < ROWS)
        *(f32x4*)&hfin[r16][c0 + 4 * q] = cap;
    __syncthreads();

    // FC: thread (r, c) computes out[b0+r][c].  512 = 4 rows x 128 slots.
    const int r = tid >> 7;      // 0..3
    const int c = tid & 127;     // 0..127
    if (c < VOCAB) {
        const float4* hv = (const float4*)hfin[r];
        const float4* wf = (const float4*)(W_fc + c * HIDDEN);
        float a0 = 0.f, a1 = 0.f, a2 = 0.f, a3 = 0.f;
#pragma unroll
        for (int j = 0; j < HIDDEN / 4; ++j) {
            float4 h = hv[j];
            float4 w = wf[j];
            a0 += h.x * w.x; a1 += h.y * w.y; a2 += h.z * w.z; a3 += h.w * w.w;
        }
        out[(b0 + r) * VOCAB + c] = (a0 + a1) + (a2 + a3) + b_fc[c];
    }
}

extern "C" void kernel_launch(void* const* d_in, const int* in_sizes, int n_in,
                              void* d_out, int out_size, void* d_ws, size_t ws_size,
                              hipStream_t stream) {
    const int* x = (const int*)d_in[0];          // [B, T] int32
    const int* lengths = (const int*)d_in[1];    // [B] int32
    const float* emb = (const float*)d_in[2];    // [V, H]
    const float* W_ih = (const float*)d_in[3];   // [H, H]
    const float* W_hh = (const float*)d_in[4];   // [H, H]
    const float* W_fc = (const float*)d_in[5];   // [V, H]
    const float* b_fc = (const float*)d_in[6];   // [V]
    float* out = (float*)d_out;                  // [B, V]

    float* embW = (float*)d_ws;                  // VOCAB*HIDDEN floats (30 KB)

    rnn_prep_embw<<<VOCAB, HIDDEN, 0, stream>>>(emb, W_ih, embW);
    rnn_mfma<<<BATCH / ROWS, 512, 0, stream>>>(x, lengths, embW, W_hh, W_fc, b_fc, out);
}

// Round 7
// 173.728 us; speedup vs baseline: 1.4066x; 1.0564x over previous
//
#include <hip/hip_runtime.h>
#include <hip/hip_bf16.h>

#define BATCH 1024
#define SEQ 256
#define HIDDEN 128
#define VOCAB 60
#define ROWS 4             // real batch rows per block (MFMA n-dim aliased 4x)
#define CHUNK 16           // ring-buffer depth in time steps
#define ASTRIDE 144        // f16 per h row: 72 dw == 8 mod 32 -> max 2-way (free)
#define RSTR 136           // f32 per ring row: 136 == 8 mod 32 -> conflict-free b128 pattern

typedef _Float16 f16x8 __attribute__((ext_vector_type(8)));
typedef _Float16 f16x4 __attribute__((ext_vector_type(4)));
typedef float f32x4 __attribute__((ext_vector_type(4)));

__device__ __forceinline__ float fast_tanh(float x) {
    // tanh(x) = 1 - 2/(exp(2x)+1); exp(2x)=exp2(x*2*log2e). Branch-free, exact +-1 tails.
    float e = __builtin_amdgcn_exp2f(x * 2.8853900817779268f);
    return __builtin_fmaf(-2.0f, __builtin_amdgcn_rcpf(e + 1.0f), 1.0f);
}

__device__ __forceinline__ f32x4 MF(f16x8 a, f16x8 b, f32x4 c) {
    return __builtin_amdgcn_mfma_f32_16x16x32_f16(a, b, c, 0, 0, 0);
}

// lgkm-only barrier (R19-isolated: saves the vmcnt(0) drain __syncthreads
// would impose). All in-loop cross-wave traffic is LDS; the chunk's VMEM
// prefetch is consumed by the SAME thread (reg->ds_write), so compiler
// vmcnt waits already order it -- no barrier drain needed.
#define LGKM_BARRIER() asm volatile("s_waitcnt lgkmcnt(0)\n\ts_barrier" ::: "memory")

// embW[v][i] = sum_j emb[v][j] * W_ih[i][j]  (fp32-exact input-projection table)
__global__ void rnn_prep_embw(const float* __restrict__ emb,
                              const float* __restrict__ W_ih,
                              float* __restrict__ embW) {
    const int v = blockIdx.x;
    const int i = threadIdx.x;
    __shared__ __align__(16) float e[HIDDEN];
    e[i] = emb[v * HIDDEN + i];
    __syncthreads();
    const float4* wrow = (const float4*)(W_ih + i * HIDDEN);
    const float4* e4 = (const float4*)e;
    float a0 = 0.f, a1 = 0.f, a2 = 0.f, a3 = 0.f;
#pragma unroll
    for (int j = 0; j < HIDDEN / 4; ++j) {
        float4 w = wrow[j];
        float4 h = e4[j];
        a0 += w.x * h.x; a1 += w.y * h.y; a2 += w.z * h.z; a3 += w.w * h.w;
    }
    embW[v * HIDDEN + i] = (a0 + a1) + (a2 + a3);
}

// R22 = CHAMPION STRUCTURE (R14, 101.4 us) + three strictly-subtractive
// micro-cuts. 256 blocks x 512 threads (8 waves, 2/SIMD), 4 batch rows per
// block, transposed recurrence z^T = W_hh * h^T, dedup'd ring staging.
// Micro-cuts: (1) lgkm-only step & boundary barriers (no vmcnt(0) drain);
// (2) 4 independent MFMA accumulators + tree-add (one MFMA-latency off the
// tail); (3) length-capture moved after the barrier (overlaps next step's
// H-read latency). Ledger: 16 structural variants (waves/rows/cg-pairing/
// VMEM seeds spread+burst/dual-problem/co-residency/barrier-free) all
// regressed; step floor = DS-burst (48 x ~10cyc, per-CU pipe) + cross-wave
// h round-trip tail (~470cyc).
__global__ void __launch_bounds__(512)
rnn_mfma(const int* __restrict__ x, const int* __restrict__ lengths,
         const float* __restrict__ embW, const float* __restrict__ W_hh,
         const float* __restrict__ W_fc, const float* __restrict__ b_fc,
         float* __restrict__ out) {
    const int tid = threadIdx.x;
    const int wave = tid >> 6;   // 0..7
    const int lane = tid & 63;
    const int q = lane >> 4;     // 0..3
    const int r16 = lane & 15;   // MFMA n index
    const int r4 = r16 & 3;      // real batch row (aliased 4x)
    const int c0 = wave * 16;    // wave's 16 z-cols
    const int b0 = blockIdx.x * ROWS;

    __shared__ __align__(16) float ring[CHUNK][ROWS][RSTR];   // 34816 B
    __shared__ __align__(16) _Float16 Ah[2][ROWS][ASTRIDE];   // 2304 B
    __shared__ int xs[ROWS][SEQ + 1];                         // 4112 B
    __shared__ __align__(16) float hfin[ROWS][HIDDEN];        // 2048 B
    __shared__ int lenbuf[ROWS];

    // Stage tokens + lengths; zero both h buffers.
    for (int idx = tid; idx < ROWS * SEQ; idx += 512) {
        int r = idx >> 8, t = idx & (SEQ - 1);
        xs[r][t] = x[(b0 + r) * SEQ + t];
    }
    if (tid < ROWS) lenbuf[tid] = lengths[b0 + tid];
    for (int idx = tid; idx < (int)(sizeof(Ah) / 4); idx += 512)
        ((int*)Ah)[idx] = 0;

    // Static A-frags of W_hh for this wave's 16-col slice:
    // A[m=r16][k=kc*32+q*8+j] = W_hh[c0 + r16][kc*32 + q*8 + j]. 16 VGPRs.
    f16x8 Wf[4];
    {
        const float* wrow = W_hh + (c0 + r16) * HIDDEN + q * 8;
#pragma unroll
        for (int kc = 0; kc < 4; ++kc) {
            const float* p = wrow + kc * 32;
#pragma unroll
            for (int j = 0; j < 8; ++j) Wf[kc][j] = (_Float16)p[j];
        }
    }

    __syncthreads();  // xs / lenbuf / Ah visible (once; full drain harmless here)

    const int mylen = lenbuf[r4];
    int lenmax = 0;
#pragma unroll
    for (int r = 0; r < ROWS; ++r) lenmax = max(lenmax, lenbuf[r]);

    // Staging-thread mapping: idx = tid + 512k -> (tp, r, c4).
    const int s_c4 = tid & 31;
    const int s_r = (tid >> 5) & 3;
    const int s_tp = tid >> 7;   // 0..3, +4 per k

    // Prefetch chunk 0 seeds into registers (dedup'd, coalesced).
    f32x4 rg[4];
#pragma unroll
    for (int k = 0; k < 4; ++k) {
        int tp = s_tp + 4 * k;
        int tok = xs[s_r][tp];
        rg[k] = *(const f32x4*)(embW + tok * HIDDEN + s_c4 * 4);
    }

    int cur = 0;
    f32x4 cap = {0.f, 0.f, 0.f, 0.f};

    for (int t0 = 0; t0 < lenmax; t0 += CHUNK) {
        // Boundary: staged regs -> ring (LDS only; reg use forces the
        // compiler's own vmcnt waits), then lgkm-only barrier.
#pragma unroll
        for (int k = 0; k < 4; ++k)
            *(f32x4*)&ring[s_tp + 4 * k][s_r][s_c4 * 4] = rg[k];
        LGKM_BARRIER();

        // Issue next chunk's global loads now; they complete during the
        // first couple of steps. Step barriers are lgkm-only, so they are
        // never force-drained -- they coast until the reg->ring write at
        // the next boundary.
        if (t0 + CHUNK < lenmax) {
            const int t0n = t0 + CHUNK;
#pragma unroll
            for (int k = 0; k < 4; ++k) {
                int tp = s_tp + 4 * k;
                int tok = xs[s_r][t0n + tp];
                rg[k] = *(const f32x4*)(embW + tok * HIDDEN + s_c4 * 4);
            }
        }

        const int tend = (lenmax - t0 < CHUNK) ? lenmax - t0 : CHUNK;
        for (int tt = 0; tt < tend; ++tt) {
            // h B-frags: B[k][n=r16] = h[r4][k] (4-way broadcast, conflict-free).
            const _Float16* hb = &Ah[cur][r4][q * 8];
            f16x8 H0 = *(const f16x8*)(hb + 0);
            f16x8 H1 = *(const f16x8*)(hb + 32);
            f16x8 H2 = *(const f16x8*)(hb + 64);
            f16x8 H3 = *(const f16x8*)(hb + 96);

            // Seed: one conflict-free b128 from the ring, feeds chain-0's C.
            f32x4 a = *(const f32x4*)&ring[tt][r4][c0 + 4 * q];
            f32x4 zb = {0.f, 0.f, 0.f, 0.f};
            f32x4 zc = {0.f, 0.f, 0.f, 0.f};
            f32x4 zd = {0.f, 0.f, 0.f, 0.f};
            // 4 independent MFMAs (no 2-deep accumulate chains): the last
            // result lands one MFMA-latency earlier; costs 2 extra f32x4 adds.
            a  = MF(Wf[0], H0, a);
            zb = MF(Wf[1], H1, zb);
            zc = MF(Wf[2], H2, zc);
            zd = MF(Wf[3], H3, zd);
            f32x4 z = (a + zb) + (zc + zd);

            f32x4 th;
            th[0] = fast_tanh(z[0]);
            th[1] = fast_tanh(z[1]);
            th[2] = fast_tanh(z[2]);
            th[3] = fast_tanh(z[3]);

            uint2 pk;
            pk.x = __builtin_bit_cast(unsigned int, __builtin_amdgcn_cvt_pkrtz(th[0], th[1]));
            pk.y = __builtin_bit_cast(unsigned int, __builtin_amdgcn_cvt_pkrtz(th[2], th[3]));

            const int nxt = cur ^ 1;
            if (r16 < ROWS)  // one writer per (row, col-quad)
                *(uint2*)&Ah[nxt][r16][c0 + 4 * q] = pk;
            LGKM_BARRIER();
            // Capture off the critical path: overlaps next step's H-read
            // latency instead of delaying the barrier.
            if (t0 + tt + 1 == mylen) cap = th;
            cur = nxt;
        }
    }

    // Final h (fp32 captures) -> hfin, then FC epilogue.
    if (r16 < ROWS)
        *(f32x4*)&hfin[r16][c0 + 4 * q] = cap;
    __syncthreads();

    // FC: thread (r, c) computes out[b0+r][c].  512 = 4 rows x 128 slots.
    const int r = tid >> 7;      // 0..3
    const int c = tid & 127;     // 0..127
    if (c < VOCAB) {
        const float4* hv = (const float4*)hfin[r];
        const float4* wf = (const float4*)(W_fc + c * HIDDEN);
        float a0 = 0.f, a1 = 0.f, a2 = 0.f, a3 = 0.f;
#pragma unroll
        for (int j = 0; j < HIDDEN / 4; ++j) {
            float4 h = hv[j];
            float4 w = wf[j];
            a0 += h.x * w.x; a1 += h.y * w.y; a2 += h.z * w.z; a3 += h.w * w.w;
        }
        out[(b0 + r) * VOCAB + c] = (a0 + a1) + (a2 + a3) + b_fc[c];
    }
}

extern "C" void kernel_launch(void* const* d_in, const int* in_sizes, int n_in,
                              void* d_out, int out_size, void* d_ws, size_t ws_size,
                              hipStream_t stream) {
    const int* x = (const int*)d_in[0];          // [B, T] int32
    const int* lengths = (const int*)d_in[1];    // [B] int32
    const float* emb = (const float*)d_in[2];    // [V, H]
    const float* W_ih = (const float*)d_in[3];   // [H, H]
    const float* W_hh = (const float*)d_in[4];   // [H, H]
    const float* W_fc = (const float*)d_in[5];   // [V, H]
    const float* b_fc = (const float*)d_in[6];   // [V]
    float* out = (float*)d_out;                  // [B, V]

    float* embW = (float*)d_ws;                  // VOCAB*HIDDEN floats (30 KB)

    rnn_prep_embw<<<VOCAB, HIDDEN, 0, stream>>>(emb, W_ih, embW);
    rnn_mfma<<<BATCH / ROWS, 512, 0, stream>>>(x, lengths, embW, W_hh, W_fc, b_fc, out);
}

// Round 8
// 160.622 us; speedup vs baseline: 1.5214x; 1.0816x over previous
//
#include <hip/hip_runtime.h>
#include <hip/hip_bf16.h>

#define BATCH 1024
#define SEQ 256
#define HIDDEN 128
#define VOCAB 60
#define ROWS 4             // real batch rows per block (MFMA n-dim aliased 4x)
#define CHUNK 16           // ring-buffer depth in time steps
#define ASTRIDE 144        // f16 per h row: 72 dw == 8 mod 32 -> max 2-way (free)
#define RSTR 136           // f32 per ring row: 136 == 8 mod 32 -> conflict-free b128 pattern

typedef _Float16 f16x8 __attribute__((ext_vector_type(8)));
typedef _Float16 f16x4 __attribute__((ext_vector_type(4)));
typedef float f32x4 __attribute__((ext_vector_type(4)));

__device__ __forceinline__ float fast_tanh(float x) {
    // tanh(x) = 1 - 2/(exp(2x)+1); exp(2x)=exp2(x*2*log2e). Branch-free, exact +-1 tails.
    float e = __builtin_amdgcn_exp2f(x * 2.8853900817779268f);
    return __builtin_fmaf(-2.0f, __builtin_amdgcn_rcpf(e + 1.0f), 1.0f);
}

// embW[v][i] = sum_j emb[v][j] * W_ih[i][j]  (fp32-exact input-projection table)
__global__ void rnn_prep_embw(const float* __restrict__ emb,
                              const float* __restrict__ W_ih,
                              float* __restrict__ embW) {
    const int v = blockIdx.x;
    const int i = threadIdx.x;
    __shared__ __align__(16) float e[HIDDEN];
    e[i] = emb[v * HIDDEN + i];
    __syncthreads();
    const float4* wrow = (const float4*)(W_ih + i * HIDDEN);
    const float4* e4 = (const float4*)e;
    float a0 = 0.f, a1 = 0.f, a2 = 0.f, a3 = 0.f;
#pragma unroll
    for (int j = 0; j < HIDDEN / 4; ++j) {
        float4 w = wrow[j];
        float4 h = e4[j];
        a0 += w.x * h.x; a1 += w.y * h.y; a2 += w.z * h.z; a3 += w.w * h.w;
    }
    embW[v * HIDDEN + i] = (a0 + a1) + (a2 + a3);
}

// CHAMPION STRUCTURE (R14, 101.4 us kernel): 256 blocks x 512 threads
// (8 waves, 2/SIMD), 4 batch rows per block, 1 block/CU.
// Transposed recurrence z^T = W_hh * h^T; wave w owns z-cols [16w,16w+16).
// MFMA n-dim (16) aliases the 4 real rows 4x (broadcast reads, free); only
// r16<4 lanes write h. Seed staging is software-pipelined: global embW loads
// for chunk k+1 issue into registers right after chunk k's boundary barrier
// and drain ~1000 cyc later at a step barrier (L2 latency fully hidden);
// the boundary itself only writes regs->ring. All in-loop traffic is
// conflict-free LDS (24K total conflicts measured).
// Measured floor: step = DS-pipe ~500 clk + exposed serial chain ~450 clk.
// SEVENTEEN structural variants across two sessions all regressed:
// waves(4/8), rows, cg-pairing, VMEM seeds (spread R19 / burst R21),
// dual-problem ILP (R20), co-residency, barrier-free, lgkm-only barriers +
// MFMA-split + capture-move (R22). Counters at this floor: MfmaUtil ~10%,
// VALUBusy ~29%, HBM ~0.17% -- no HW pipe near limit; the bound is the
// lockstep serial h round-trip, not a roofline.
__global__ void __launch_bounds__(512)
rnn_mfma(const int* __restrict__ x, const int* __restrict__ lengths,
         const float* __restrict__ embW, const float* __restrict__ W_hh,
         const float* __restrict__ W_fc, const float* __restrict__ b_fc,
         float* __restrict__ out) {
    const int tid = threadIdx.x;
    const int wave = tid >> 6;   // 0..7
    const int lane = tid & 63;
    const int q = lane >> 4;     // 0..3
    const int r16 = lane & 15;   // MFMA n index
    const int r4 = r16 & 3;      // real batch row (aliased 4x)
    const int c0 = wave * 16;    // wave's 16 z-cols
    const int b0 = blockIdx.x * ROWS;

    __shared__ __align__(16) float ring[CHUNK][ROWS][RSTR];   // 34816 B
    __shared__ __align__(16) _Float16 Ah[2][ROWS][ASTRIDE];   // 2304 B
    __shared__ int xs[ROWS][SEQ + 1];                         // 4112 B
    __shared__ __align__(16) float hfin[ROWS][HIDDEN];        // 2048 B
    __shared__ int lenbuf[ROWS];

    // Stage tokens + lengths; zero both h buffers.
    for (int idx = tid; idx < ROWS * SEQ; idx += 512) {
        int r = idx >> 8, t = idx & (SEQ - 1);
        xs[r][t] = x[(b0 + r) * SEQ + t];
    }
    if (tid < ROWS) lenbuf[tid] = lengths[b0 + tid];
    for (int idx = tid; idx < (int)(sizeof(Ah) / 4); idx += 512)
        ((int*)Ah)[idx] = 0;

    // Static A-frags of W_hh for this wave's 16-col slice:
    // A[m=r16][k=kc*32+q*8+j] = W_hh[c0 + r16][kc*32 + q*8 + j]. 16 VGPRs.
    f16x8 Wf[4];
    {
        const float* wrow = W_hh + (c0 + r16) * HIDDEN + q * 8;
#pragma unroll
        for (int kc = 0; kc < 4; ++kc) {
            const float* p = wrow + kc * 32;
#pragma unroll
            for (int j = 0; j < 8; ++j) Wf[kc][j] = (_Float16)p[j];
        }
    }

    __syncthreads();  // xs / lenbuf / Ah visible

    const int mylen = lenbuf[r4];
    int lenmax = 0;
#pragma unroll
    for (int r = 0; r < ROWS; ++r) lenmax = max(lenmax, lenbuf[r]);

    // Staging-thread mapping: idx = tid + 512k -> (tp, r, c4).
    const int s_c4 = tid & 31;
    const int s_r = (tid >> 5) & 3;
    const int s_tp = tid >> 7;   // 0..3, +4 per k

    // Prefetch chunk 0 seeds into registers.
    f32x4 rg[4];
#pragma unroll
    for (int k = 0; k < 4; ++k) {
        int tp = s_tp + 4 * k;
        int tok = xs[s_r][tp];
        rg[k] = *(const f32x4*)(embW + tok * HIDDEN + s_c4 * 4);
    }

    int cur = 0;
    f32x4 cap = {0.f, 0.f, 0.f, 0.f};

    for (int t0 = 0; t0 < lenmax; t0 += CHUNK) {
        // Boundary: staged regs -> ring (LDS only, cheap), then barrier.
#pragma unroll
        for (int k = 0; k < 4; ++k)
            *(f32x4*)&ring[s_tp + 4 * k][s_r][s_c4 * 4] = rg[k];
        __syncthreads();

        // Issue next chunk's global loads now; they complete during the
        // first couple of steps and drain harmlessly at a step barrier.
        if (t0 + CHUNK < lenmax) {
            const int t0n = t0 + CHUNK;
#pragma unroll
            for (int k = 0; k < 4; ++k) {
                int tp = s_tp + 4 * k;
                int tok = xs[s_r][t0n + tp];
                rg[k] = *(const f32x4*)(embW + tok * HIDDEN + s_c4 * 4);
            }
        }

        const int tend = (lenmax - t0 < CHUNK) ? lenmax - t0 : CHUNK;
        for (int tt = 0; tt < tend; ++tt) {
            // h B-frags: B[k][n=r16] = h[r4][k] (4-way broadcast, conflict-free).
            const _Float16* hb = &Ah[cur][r4][q * 8];
            f16x8 H0 = *(const f16x8*)(hb + 0);
            f16x8 H1 = *(const f16x8*)(hb + 32);
            f16x8 H2 = *(const f16x8*)(hb + 64);
            f16x8 H3 = *(const f16x8*)(hb + 96);

            // Seed: one conflict-free b128 from the ring, feeds C directly.
            f32x4 a = *(const f32x4*)&ring[tt][r4][c0 + 4 * q];
            f32x4 d = {0.f, 0.f, 0.f, 0.f};
            a = __builtin_amdgcn_mfma_f32_16x16x32_f16(Wf[0], H0, a, 0, 0, 0);
            d = __builtin_amdgcn_mfma_f32_16x16x32_f16(Wf[2], H2, d, 0, 0, 0);
            a = __builtin_amdgcn_mfma_f32_16x16x32_f16(Wf[1], H1, a, 0, 0, 0);
            d = __builtin_amdgcn_mfma_f32_16x16x32_f16(Wf[3], H3, d, 0, 0, 0);
            f32x4 z = a + d;

            f32x4 th;
            th[0] = fast_tanh(z[0]);
            th[1] = fast_tanh(z[1]);
            th[2] = fast_tanh(z[2]);
            th[3] = fast_tanh(z[3]);

            uint2 pk;
            pk.x = __builtin_bit_cast(unsigned int, __builtin_amdgcn_cvt_pkrtz(th[0], th[1]));
            pk.y = __builtin_bit_cast(unsigned int, __builtin_amdgcn_cvt_pkrtz(th[2], th[3]));

            const int nxt = cur ^ 1;
            if (r16 < ROWS)  // one writer per (row, col-quad)
                *(uint2*)&Ah[nxt][r16][c0 + 4 * q] = pk;
            // Capture off the critical path (after the write).
            if (t0 + tt + 1 == mylen) cap = th;
            __syncthreads();
            cur = nxt;
        }
    }

    // Final h (fp32 captures) -> hfin, then FC epilogue.
    if (r16 < ROWS)
        *(f32x4*)&hfin[r16][c0 + 4 * q] = cap;
    __syncthreads();

    // FC: thread (r, c) computes out[b0+r][c].  512 = 4 rows x 128 slots.
    const int r = tid >> 7;      // 0..3
    const int c = tid & 127;     // 0..127
    if (c < VOCAB) {
        const float4* hv = (const float4*)hfin[r];
        const float4* wf = (const float4*)(W_fc + c * HIDDEN);
        float a0 = 0.f, a1 = 0.f, a2 = 0.f, a3 = 0.f;
#pragma unroll
        for (int j = 0; j < HIDDEN / 4; ++j) {
            float4 h = hv[j];
            float4 w = wf[j];
            a0 += h.x * w.x; a1 += h.y * w.y; a2 += h.z * w.z; a3 += h.w * w.w;
        }
        out[(b0 + r) * VOCAB + c] = (a0 + a1) + (a2 + a3) + b_fc[c];
    }
}

extern "C" void kernel_launch(void* const* d_in, const int* in_sizes, int n_in,
                              void* d_out, int out_size, void* d_ws, size_t ws_size,
                              hipStream_t stream) {
    const int* x = (const int*)d_in[0];          // [B, T] int32
    const int* lengths = (const int*)d_in[1];    // [B] int32
    const float* emb = (const float*)d_in[2];    // [V, H]
    const float* W_ih = (const float*)d_in[3];   // [H, H]
    const float* W_hh = (const float*)d_in[4];   // [H, H]
    const float* W_fc = (const float*)d_in[5];   // [V, H]
    const float* b_fc = (const float*)d_in[6];   // [V]
    float* out = (float*)d_out;                  // [B, V]

    float* embW = (float*)d_ws;                  // VOCAB*HIDDEN floats (30 KB)

    rnn_prep_embw<<<VOCAB, HIDDEN, 0, stream>>>(emb, W_ih, embW);
    rnn_mfma<<<BATCH / ROWS, 512, 0, stream>>>(x, lengths, embW, W_hh, W_fc, b_fc, out);
}